// Round 5
// baseline (416.775 us; speedup 1.0000x reference)
//
#include <hip/hip_runtime.h>
#include <math.h>

#define NB   8
#define BC   32
#define WIN  14
#define HH   16
#define BKK  288     // 32*3*3
#define CWW  1152    // 32*6*6
#define NXY  36
#define NBLK 1152    // 8 b x 36 xy x 4 cquarter
#define EPSF 1e-10f
#define LOG2E 1.4426950408889634f
#define LN2   0.6931471805599453f
#define L2SQ2PI 1.3257480647361593f  // log2(sqrt(2*pi))

__device__ __forceinline__ float ex2(float x) { return __builtin_amdgcn_exp2f(x); }
__device__ __forceinline__ float lg2(float x) { return __builtin_amdgcn_logf(x); }
__device__ __forceinline__ float rcpf(float x) { return __builtin_amdgcn_rcpf(x); }

__device__ __forceinline__ float red16(float v) {
    v += __shfl_xor(v, 1);
    v += __shfl_xor(v, 2);
    v += __shfl_xor(v, 4);
    v += __shfl_xor(v, 8);
    return v;
}

__device__ __forceinline__ float4 f4mul(float s, float4 b) {
    return make_float4(s * b.x, s * b.y, s * b.z, s * b.w);
}
__device__ __forceinline__ float4 f4fma(float s, float4 b, float4 c) {
    return make_float4(fmaf(s, b.x, c.x), fmaf(s, b.y, c.y),
                       fmaf(s, b.z, c.z), fmaf(s, b.w, c.w));
}

// Per-b barrier: 144 blocks arrive. No fences: cross-block data (rowsG) is
// written/read exclusively with agent-scope atomics (coherence-point ops),
// so no cache maintenance is needed; caches stay warm (round-4-proven).
__device__ __forceinline__ void b_barrier(unsigned* cnt, unsigned* gen) {
    __syncthreads();
    if (threadIdx.x == 0) {
        unsigned g = __hip_atomic_load(gen, __ATOMIC_RELAXED, __HIP_MEMORY_SCOPE_AGENT);
        unsigned prev = __hip_atomic_fetch_add(cnt, 1u, __ATOMIC_ACQ_REL, __HIP_MEMORY_SCOPE_AGENT);
        if (prev == 143u) {
            __hip_atomic_store(cnt, 0u, __ATOMIC_RELAXED, __HIP_MEMORY_SCOPE_AGENT);
            __hip_atomic_fetch_add(gen, 1u, __ATOMIC_RELEASE, __HIP_MEMORY_SCOPE_AGENT);
        } else {
            while (__hip_atomic_load(gen, __ATOMIC_RELAXED, __HIP_MEMORY_SCOPE_AGENT) == g)
                __builtin_amdgcn_s_sleep(2);
        }
    }
    __syncthreads();
}

// W[m][c][p][q] (float4 rows over q) -> Wt[m][p][c] (float4 over q).
// Also zero-inits rowsG and the barrier slots each launch (ws is poisoned;
// graph replay needs re-zero). Dispatch boundary makes these visible.
__global__ __launch_bounds__(256)
void wt_kernel(const float4* __restrict__ W4, float4* __restrict__ Wt4,
               float* __restrict__ rowsZ, unsigned* __restrict__ barz) {
    int o = blockIdx.x * 256 + threadIdx.x;   // 288*4*32 = 36864
    if (o < 2 * NB * BKK) rowsZ[o] = 0.0f;
    if (o < 256) barz[o] = 0u;
    if (o < BKK * 128) {
        int c = o & 31, p = (o >> 5) & 3, m = o >> 7;
        Wt4[o] = W4[(m * 32 + c) * 4 + p];
    }
}

// ---------------------------------------------------------------------------
// Fused EM, 1152 blocks = (b, xy, cq), b = bid&7 (XCD swizzle), 256 thr =
// 8 c x 32 mchunks (9 m each). 3 EM iterations in-kernel; psv in LDS
// (round-4-proven codegen: unroll 3, no software prefetch -> no scratch);
// cross-block row sums via agent-scope fp32 atomicAdd + per-b spin barriers;
// zero threadfence -> L2 stays warm.
// LDS 31520 B -> alloc <=32768 -> 5 blocks/CU; launch_bounds(256,5) caps
// VGPR for 5 waves/SIMD -> 1280 capacity >= 1152 co-resident, deadlock-free.
// ---------------------------------------------------------------------------
__global__ __launch_bounds__(256, 5)
void fused_em(const float* __restrict__ poses,
              const float* __restrict__ act,
              const float4* __restrict__ Wt4,
              const float* __restrict__ beta_v,
              const float* __restrict__ beta_a,
              const float* __restrict__ lam,
              float* __restrict__ rowsG,     // [2][b][288] atomic row sums
              unsigned* __restrict__ bar,    // [8][32] per-b cnt/gen
              float* __restrict__ mu_out,    // [b][n][16]
              float* __restrict__ a_out)     // [b][n]
{
    __shared__ float4 poseS4[BKK * 4];                 // 18432 B
    __shared__ float2 AE[BKK];                         //  2304 B (am*invR, EPS*am)
    __shared__ float  muL[8][16];                      //   512 B
    __shared__ float  KL[8][16];
    __shared__ float  CL[8][16];
    __shared__ float  aL[8];                           //    32 B
    __shared__ __align__(16) float uni[BKK * 8];       //  9216 B: psvL[m*8+c_l] U red[1152]

    const int bid = blockIdx.x;             // 1152
    const int b   = bid & 7;                // XCD swizzle: batch <-> XCD
    const int idx = bid >> 3;               // 0..143
    const int cq  = idx & 3;                // c quarter
    const int xy  = idx >> 2;               // 0..35
    const int X = xy / 6, Y = xy % 6;

    const int tid = threadIdx.x;
    const int c_l = tid & 7;                // 0..7
    const int mch = tid >> 3;               // 0..31
    const int c   = cq * 8 + c_l;
    const int m0  = mch * 9;

    const float4* poses4 = reinterpret_cast<const float4*>(poses);
    for (int i2 = tid; i2 < BKK * 4; i2 += 256) {
        int m = i2 >> 2, q = i2 & 3;
        int B = m / 9, uv = m % 9, u = uv / 3, v = uv % 3;
        poseS4[i2] = poses4[((b * BC + B) * 196 + (2 * Y + u) * WIN + (2 * X + v)) * 4 + q];
    }
    for (int m = tid; m < BKK; m += 256) {
        int B = m / 9, uv = m % 9, u = uv / 3, v = uv % 3;
        float am = act[(b * BC + B) * 196 + (2 * Y + u) * WIN + (2 * X + v)];
        AE[m] = make_float2(am * (1.0f / 32.0f), 0.0f);   // it==0: R = 1/32
    }
    for (int i2 = tid; i2 < BKK * 8; i2 += 256) uni[i2] = 0.0f;
    if (tid < 8) aL[tid] = 0.0f;
    __syncthreads();

    const float4* WtB  = Wt4 + c;           // + m*128 + p*32
    const float   lamv = lam[0];
    float4* red4 = reinterpret_cast<float4*>(uni);
    unsigned* bcnt = bar + b * 32;
    unsigned* bgen = bar + b * 32 + 16;

    for (int it = 0; it < 3; ++it) {
        // ========================= stats =========================
        const float ap_n = aL[c_l];         // zero-inited at it==0 (unused there)
        float  sum_R = 0.0f;
        float4 sRV[4]  = {make_float4(0,0,0,0), make_float4(0,0,0,0),
                          make_float4(0,0,0,0), make_float4(0,0,0,0)};
        float4 sRV2[4] = {make_float4(0,0,0,0), make_float4(0,0,0,0),
                          make_float4(0,0,0,0), make_float4(0,0,0,0)};
        #pragma unroll 3
        for (int i = 0; i < 9; ++i) {
            const int m = m0 + i;
            float4 w0 = WtB[m * 128 +  0];
            float4 w1 = WtB[m * 128 + 32];
            float4 w2 = WtB[m * 128 + 64];
            float4 w3 = WtB[m * 128 + 96];
            float4 P0 = poseS4[m * 4 + 0];
            float4 P1 = poseS4[m * 4 + 1];
            float4 P2 = poseS4[m * 4 + 2];
            float4 P3 = poseS4[m * 4 + 3];
            float4 V0 = f4fma(w0.w, P3, f4fma(w0.z, P2, f4fma(w0.y, P1, f4mul(w0.x, P0))));
            float4 V1 = f4fma(w1.w, P3, f4fma(w1.z, P2, f4fma(w1.y, P1, f4mul(w1.x, P0))));
            float4 V2 = f4fma(w2.w, P3, f4fma(w2.z, P2, f4fma(w2.y, P1, f4mul(w2.x, P0))));
            float4 V3 = f4fma(w3.w, P3, f4fma(w3.z, P2, f4fma(w3.y, P1, f4mul(w3.x, P0))));
            float2 ae = AE[m];
            float Ra;
            if (it == 0) Ra = ae.x;
            else         Ra = fmaf(ap_n * uni[m * 8 + c_l], ae.x, ae.y);
            sum_R += Ra;
            sRV[0] = f4fma(Ra, V0, sRV[0]);
            sRV[1] = f4fma(Ra, V1, sRV[1]);
            sRV[2] = f4fma(Ra, V2, sRV[2]);
            sRV[3] = f4fma(Ra, V3, sRV[3]);
            float4 q0 = make_float4(V0.x*V0.x, V0.y*V0.y, V0.z*V0.z, V0.w*V0.w);
            float4 q1 = make_float4(V1.x*V1.x, V1.y*V1.y, V1.z*V1.z, V1.w*V1.w);
            float4 q2 = make_float4(V2.x*V2.x, V2.y*V2.y, V2.z*V2.z, V2.w*V2.w);
            float4 q3 = make_float4(V3.x*V3.x, V3.y*V3.y, V3.z*V3.z, V3.w*V3.w);
            sRV2[0] = f4fma(Ra, q0, sRV2[0]);
            sRV2[1] = f4fma(Ra, q1, sRV2[1]);
            sRV2[2] = f4fma(Ra, q2, sRV2[2]);
            sRV2[3] = f4fma(Ra, q3, sRV2[3]);
        }

        // combine the 8 mchunks within each wave (lane bits 3,4,5)
        {
            float* f1 = reinterpret_cast<float*>(sRV);
            float* f2 = reinterpret_cast<float*>(sRV2);
            #pragma unroll
            for (int k = 0; k < 16; ++k) { f1[k] += __shfl_xor(f1[k], 8);  f2[k] += __shfl_xor(f2[k], 8); }
            sum_R += __shfl_xor(sum_R, 8);
            #pragma unroll
            for (int k = 0; k < 16; ++k) { f1[k] += __shfl_xor(f1[k], 16); f2[k] += __shfl_xor(f2[k], 16); }
            sum_R += __shfl_xor(sum_R, 16);
            #pragma unroll
            for (int k = 0; k < 16; ++k) { f1[k] += __shfl_xor(f1[k], 32); f2[k] += __shfl_xor(f2[k], 32); }
            sum_R += __shfl_xor(sum_R, 32);
        }
        __syncthreads();                    // all psvL reads done before red overwrite
        if ((tid & 56) == 0) {              // lane 0..7 of each wave
            float4* dst = &red4[((tid >> 6) * 8 + c_l) * 9];
            dst[0] = make_float4(sum_R, 0.f, 0.f, 0.f);
            dst[1] = sRV[0];  dst[2] = sRV[1];  dst[3] = sRV[2];  dst[4] = sRV[3];
            dst[5] = sRV2[0]; dst[6] = sRV2[1]; dst[7] = sRV2[2]; dst[8] = sRV2[3];
        }
        __syncthreads();

        // -------- epilogue: thread = (h, cc), cc<8 active --------
        {
            const int h  = tid & 15;
            const int cc = tid >> 4;
            if (cc < 8) {
                float sR = 0.f, sV = 0.f, sV2 = 0.f;
                #pragma unroll
                for (int j = 0; j < 4; ++j) {
                    int off = (j * 8 + cc) * 36;
                    sR  += uni[off];
                    sV  += uni[off + 4 + h];
                    sV2 += uni[off + 20 + h];
                }
                float inv = 1.0f / sR;
                float mu  = sV * inv;
                float sig = fmaxf(fmaf(-mu, mu, sV2 * inv), 1e-30f);
                float l2s = lg2(sqrtf(sig) + EPSF);          // log2(sigma+eps)
                float lsum = red16(l2s) * LN2;               // sum_h ln(sigma)
                int   cgi  = cq * 8 + cc;
                float cost = sR * fmaf(16.0f, beta_v[cgi], lsum);
                float z    = lamv * (beta_a[cgi] - cost);
                float av   = rcpf(1.0f + ex2(-z * LOG2E));
                if (it < 2) {
                    muL[cc][h] = mu;
                    KL[cc][h]  = (-0.5f * LOG2E) / sig;
                    CL[cc][h]  = -(l2s + L2SQ2PI);
                    if (h == 0) aL[cc] = av;
                } else {
                    int nn   = cgi * NXY + xy;
                    int base = (b * CWW + nn) * HH + h;
                    mu_out[base] = mu;
                    if (h == 0) a_out[b * CWW + nn] = av;
                }
            }
        }
        if (it == 2) return;
        __syncthreads();                    // muL/KL/CL/aL visible; red reads done

        // ========================= pv =========================
        float4 M[4], Kk[4], Cc[4];
        #pragma unroll
        for (int p = 0; p < 4; ++p) {
            M[p]  = make_float4(muL[c_l][4*p+0], muL[c_l][4*p+1], muL[c_l][4*p+2], muL[c_l][4*p+3]);
            Kk[p] = make_float4(KL[c_l][4*p+0],  KL[c_l][4*p+1],  KL[c_l][4*p+2],  KL[c_l][4*p+3]);
            Cc[p] = make_float4(CL[c_l][4*p+0],  CL[c_l][4*p+1],  CL[c_l][4*p+2],  CL[c_l][4*p+3]);
        }
        const float ap = aL[c_l];
        float* rowsIt = rowsG + it * (NB * BKK) + b * BKK;

        #pragma unroll 3
        for (int i = 0; i < 9; ++i) {
            const int m = m0 + i;
            float4 w0 = WtB[m * 128 +  0];
            float4 w1 = WtB[m * 128 + 32];
            float4 w2 = WtB[m * 128 + 64];
            float4 w3 = WtB[m * 128 + 96];
            float4 P0 = poseS4[m * 4 + 0];
            float4 P1 = poseS4[m * 4 + 1];
            float4 P2 = poseS4[m * 4 + 2];
            float4 P3 = poseS4[m * 4 + 3];
            float4 V0 = f4fma(w0.w, P3, f4fma(w0.z, P2, f4fma(w0.y, P1, f4mul(w0.x, P0))));
            float4 V1 = f4fma(w1.w, P3, f4fma(w1.z, P2, f4fma(w1.y, P1, f4mul(w1.x, P0))));
            float4 V2 = f4fma(w2.w, P3, f4fma(w2.z, P2, f4fma(w2.y, P1, f4mul(w2.x, P0))));
            float4 V3 = f4fma(w3.w, P3, f4fma(w3.z, P2, f4fma(w3.y, P1, f4mul(w3.x, P0))));

            float psv = 0.0f;
            {
                float4 t, g;
                t = make_float4(V0.x-M[0].x, V0.y-M[0].y, V0.z-M[0].z, V0.w-M[0].w);
                g = make_float4(fmaf(t.x*t.x, Kk[0].x, Cc[0].x), fmaf(t.y*t.y, Kk[0].y, Cc[0].y),
                                fmaf(t.z*t.z, Kk[0].z, Cc[0].z), fmaf(t.w*t.w, Kk[0].w, Cc[0].w));
                psv += ex2(g.x) + ex2(g.y) + ex2(g.z) + ex2(g.w);
                t = make_float4(V1.x-M[1].x, V1.y-M[1].y, V1.z-M[1].z, V1.w-M[1].w);
                g = make_float4(fmaf(t.x*t.x, Kk[1].x, Cc[1].x), fmaf(t.y*t.y, Kk[1].y, Cc[1].y),
                                fmaf(t.z*t.z, Kk[1].z, Cc[1].z), fmaf(t.w*t.w, Kk[1].w, Cc[1].w));
                psv += ex2(g.x) + ex2(g.y) + ex2(g.z) + ex2(g.w);
                t = make_float4(V2.x-M[2].x, V2.y-M[2].y, V2.z-M[2].z, V2.w-M[2].w);
                g = make_float4(fmaf(t.x*t.x, Kk[2].x, Cc[2].x), fmaf(t.y*t.y, Kk[2].y, Cc[2].y),
                                fmaf(t.z*t.z, Kk[2].z, Cc[2].z), fmaf(t.w*t.w, Kk[2].w, Cc[2].w));
                psv += ex2(g.x) + ex2(g.y) + ex2(g.z) + ex2(g.w);
                t = make_float4(V3.x-M[3].x, V3.y-M[3].y, V3.z-M[3].z, V3.w-M[3].w);
                g = make_float4(fmaf(t.x*t.x, Kk[3].x, Cc[3].x), fmaf(t.y*t.y, Kk[3].y, Cc[3].y),
                                fmaf(t.z*t.z, Kk[3].z, Cc[3].z), fmaf(t.w*t.w, Kk[3].w, Cc[3].w));
                psv += ex2(g.x) + ex2(g.y) + ex2(g.z) + ex2(g.w);
            }
            uni[m * 8 + c_l] = psv;         // psvL

            float rv = ap * psv;
            rv += __shfl_xor(rv, 1);
            rv += __shfl_xor(rv, 2);
            rv += __shfl_xor(rv, 4);
            if (c_l == 0)
                __hip_atomic_fetch_add(&rowsIt[m], rv,
                                       __ATOMIC_RELAXED, __HIP_MEMORY_SCOPE_AGENT);
        }

        b_barrier(bcnt, bgen);
        asm volatile("" ::: "memory");

        // -------- AE update from completed row sums (coherent atomic loads) ----
        for (int m = tid; m < BKK; m += 256) {
            int B = m / 9, uv = m % 9, u = uv / 3, v = uv % 3;
            float am = act[(b * BC + B) * 196 + (2 * Y + u) * WIN + (2 * X + v)];
            float s = __hip_atomic_load(&rowsIt[m], __ATOMIC_RELAXED, __HIP_MEMORY_SCOPE_AGENT);
            float invr = 1.0f / (s + EPSF);
            AE[m] = make_float2(am * invr, EPSF * am);
        }
        __syncthreads();
    }
}

extern "C" void kernel_launch(void* const* d_in, const int* in_sizes, int n_in,
                              void* d_out, int out_size, void* d_ws, size_t ws_size,
                              hipStream_t stream) {
    const float* poses  = (const float*)d_in[0];
    const float* act    = (const float*)d_in[1];
    const float* W      = (const float*)d_in[2];
    const float* beta_v = (const float*)d_in[3];
    const float* beta_a = (const float*)d_in[4];
    const float* lam    = (const float*)d_in[5];
    float* out = (float*)d_out;
    float* ws  = (float*)d_ws;

    const int SZ = NB * CWW * HH;            // 147456
    float* Wt    = ws;                       // 288*128 float4 = 147456 floats
    float* rowsG = Wt + BKK * 512;           // 2*8*288 = 4608 floats
    unsigned* bar = (unsigned*)(rowsG + 2 * NB * BKK);  // 8*32 uints

    wt_kernel<<<dim3(144), dim3(256), 0, stream>>>(
        (const float4*)W, (float4*)Wt, rowsG, bar);

    const float4* Wt4 = (const float4*)Wt;
    fused_em<<<dim3(NBLK), dim3(256), 0, stream>>>(
        poses, act, Wt4, beta_v, beta_a, lam,
        rowsG, bar, out, out + SZ);
}

// Round 6
// 195.205 us; speedup vs baseline: 2.1351x; 2.1351x over previous
//
#include <hip/hip_runtime.h>
#include <math.h>

#define NB   8
#define BC   32
#define WIN  14
#define HH   16
#define BKK  288     // 32*3*3
#define CWW  1152    // 32*6*6
#define NXY  36
#define NBLK 576
#define EPSF 1e-10f
#define LOG2E 1.4426950408889634f
#define LN2   0.6931471805599453f
#define L2SQ2PI 1.3257480647361593f  // log2(sqrt(2*pi))

__device__ __forceinline__ float ex2(float x) { return __builtin_amdgcn_exp2f(x); }
__device__ __forceinline__ float lg2(float x) { return __builtin_amdgcn_logf(x); }
__device__ __forceinline__ float rcpf(float x) { return __builtin_amdgcn_rcpf(x); }

__device__ __forceinline__ float red16(float v) {
    v += __shfl_xor(v, 1);
    v += __shfl_xor(v, 2);
    v += __shfl_xor(v, 4);
    v += __shfl_xor(v, 8);
    return v;
}

__device__ __forceinline__ float4 f4mul(float s, float4 b) {
    return make_float4(s * b.x, s * b.y, s * b.z, s * b.w);
}
__device__ __forceinline__ float4 f4fma(float s, float4 b, float4 c) {
    return make_float4(fmaf(s, b.x, c.x), fmaf(s, b.y, c.y),
                       fmaf(s, b.z, c.z), fmaf(s, b.w, c.w));
}

// Per-b barrier: 72 blocks arrive. No fences: cross-block data (rowsG) is
// written/read exclusively with agent-scope atomics (coherence-point ops),
// so no cache maintenance is needed; caches stay warm (round-4-proven).
__device__ __forceinline__ void b_barrier(unsigned* cnt, unsigned* gen) {
    __syncthreads();
    if (threadIdx.x == 0) {
        unsigned g = __hip_atomic_load(gen, __ATOMIC_RELAXED, __HIP_MEMORY_SCOPE_AGENT);
        unsigned prev = __hip_atomic_fetch_add(cnt, 1u, __ATOMIC_ACQ_REL, __HIP_MEMORY_SCOPE_AGENT);
        if (prev == 71u) {
            __hip_atomic_store(cnt, 0u, __ATOMIC_RELAXED, __HIP_MEMORY_SCOPE_AGENT);
            __hip_atomic_fetch_add(gen, 1u, __ATOMIC_RELEASE, __HIP_MEMORY_SCOPE_AGENT);
        } else {
            while (__hip_atomic_load(gen, __ATOMIC_RELAXED, __HIP_MEMORY_SCOPE_AGENT) == g)
                __builtin_amdgcn_s_sleep(2);
        }
    }
    __syncthreads();
}

// W[m][c][p][q] (float4 rows over q) -> Wt[m][p][c] (float4 over q).
// Writes a zeroed slack row (m=288) so the rotation prefetch's last load is
// in-bounds. Also zero-inits rowsG and barrier slots (ws is poisoned).
__global__ __launch_bounds__(256)
void wt_kernel(const float4* __restrict__ W4, float4* __restrict__ Wt4,
               float* __restrict__ rowsZ, unsigned* __restrict__ barz) {
    int o = blockIdx.x * 256 + threadIdx.x;   // 288*4*32 = 36864
    if (o < 2 * NB * BKK) rowsZ[o] = 0.0f;
    if (o < 256) barz[o] = 0u;
    if (o < 128) Wt4[BKK * 128 + o] = make_float4(0.f, 0.f, 0.f, 0.f);  // slack row
    if (o < BKK * 128) {
        int c = o & 31, p = (o >> 5) & 3, m = o >> 7;
        Wt4[o] = W4[(m * 32 + c) * 4 + p];
    }
}

// ---------------------------------------------------------------------------
// Fused EM, one kernel, 576 blocks = (b, xy, chalf), b = bid&7 (XCD swizzle).
// 3 EM iterations in-kernel; psv in LDS; distance-1 register rotation
// prefetch of Wt in both m-loops (#pragma unroll 1 -- bounded hoisting, no
// round-3 scratch explosion); cross-block row sums via agent-scope fp32
// atomicAdd + per-b spin barriers; zero threadfence -> L2 stays warm.
// launch_bounds(256,4): VGPR<=128 -> 4-waves/SIMD tier -> 3 blocks/CU with
// LDS 44.8KB -> all 576 blocks co-resident, barrier deadlock-free.
// ---------------------------------------------------------------------------
__global__ __launch_bounds__(256, 4)
void fused_em(const float* __restrict__ poses,
              const float* __restrict__ act,
              const float4* __restrict__ Wt4,
              const float* __restrict__ beta_v,
              const float* __restrict__ beta_a,
              const float* __restrict__ lam,
              float* __restrict__ rowsG,     // [2][b][288] atomic row sums
              unsigned* __restrict__ bar,    // [8][32] per-b cnt/gen
              float* __restrict__ mu_out,    // [b][n][16]
              float* __restrict__ a_out)     // [b][n]
{
    __shared__ float4 poseS4[BKK * 4];                 // 18432 B
    __shared__ float  amL[BKK];                        //  1152 B
    __shared__ float2 AE[BKK];                         //  2304 B (am*invR, EPS*am)
    __shared__ float  muL[16][17];                     //  1088 B
    __shared__ float  KL[16][17];
    __shared__ float  CL[16][17];
    __shared__ float  aL[16];
    __shared__ __align__(16) float uni[BKK * 17];      // 19584 B: psvL[m*17+c] U red[2304]

    const int bid   = blockIdx.x;           // 576
    const int b     = bid & 7;              // XCD swizzle: batch <-> XCD
    const int idx   = bid >> 3;             // 0..71
    const int chalf = idx & 1;
    const int xy    = idx >> 1;             // 0..35
    const int X = xy / 6, Y = xy % 6;

    const int tid = threadIdx.x;
    const int c_l = tid & 15;
    const int mch = tid >> 4;               // 0..15
    const int c   = chalf * 16 + c_l;
    const int m0  = mch * 18;

    const float4* poses4 = reinterpret_cast<const float4*>(poses);
    for (int i2 = tid; i2 < BKK * 4; i2 += 256) {
        int m = i2 >> 2, q = i2 & 3;
        int B = m / 9, uv = m % 9, u = uv / 3, v = uv % 3;
        poseS4[i2] = poses4[((b * BC + B) * 196 + (2 * Y + u) * WIN + (2 * X + v)) * 4 + q];
    }
    for (int m = tid; m < BKK; m += 256) {
        int B = m / 9, uv = m % 9, u = uv / 3, v = uv % 3;
        float am = act[(b * BC + B) * 196 + (2 * Y + u) * WIN + (2 * X + v)];
        amL[m] = am;
        AE[m] = make_float2(am * (1.0f / 32.0f), 0.0f);   // it==0: R = 1/32
    }
    for (int i2 = tid; i2 < BKK * 17; i2 += 256) uni[i2] = 0.0f;
    if (tid < 16) aL[tid] = 0.0f;
    __syncthreads();

    const float4* WtB  = Wt4 + c;           // + m*128 + p*32
    const float   lamv = lam[0];
    float4* red4 = reinterpret_cast<float4*>(uni);
    unsigned* bcnt = bar + b * 32;
    unsigned* bgen = bar + b * 32 + 16;

    for (int it = 0; it < 3; ++it) {
        // ========================= stats =========================
        const float ap_n = aL[c_l];         // zero-inited at it==0 (unused there)
        float  sum_R = 0.0f;
        float4 sRV[4]  = {make_float4(0,0,0,0), make_float4(0,0,0,0),
                          make_float4(0,0,0,0), make_float4(0,0,0,0)};
        float4 sRV2[4] = {make_float4(0,0,0,0), make_float4(0,0,0,0),
                          make_float4(0,0,0,0), make_float4(0,0,0,0)};
        {
            const float4* wp = WtB + m0 * 128;
            float4 w0 = wp[0], w1 = wp[32], w2 = wp[64], w3 = wp[96];
            #pragma unroll 1
            for (int i = 0; i < 18; ++i) {
                const int m = m0 + i;
                wp += 128;                               // i=17 -> slack row 288
                float4 nw0 = wp[0], nw1 = wp[32], nw2 = wp[64], nw3 = wp[96];
                float4 P0 = poseS4[m * 4 + 0];
                float4 P1 = poseS4[m * 4 + 1];
                float4 P2 = poseS4[m * 4 + 2];
                float4 P3 = poseS4[m * 4 + 3];
                float4 V0 = f4fma(w0.w, P3, f4fma(w0.z, P2, f4fma(w0.y, P1, f4mul(w0.x, P0))));
                float4 V1 = f4fma(w1.w, P3, f4fma(w1.z, P2, f4fma(w1.y, P1, f4mul(w1.x, P0))));
                float4 V2 = f4fma(w2.w, P3, f4fma(w2.z, P2, f4fma(w2.y, P1, f4mul(w2.x, P0))));
                float4 V3 = f4fma(w3.w, P3, f4fma(w3.z, P2, f4fma(w3.y, P1, f4mul(w3.x, P0))));
                float2 ae = AE[m];
                float Ra;
                if (it == 0) Ra = ae.x;
                else         Ra = fmaf(ap_n * uni[m * 17 + c_l], ae.x, ae.y);
                sum_R += Ra;
                sRV[0] = f4fma(Ra, V0, sRV[0]);
                sRV[1] = f4fma(Ra, V1, sRV[1]);
                sRV[2] = f4fma(Ra, V2, sRV[2]);
                sRV[3] = f4fma(Ra, V3, sRV[3]);
                float4 q0 = make_float4(V0.x*V0.x, V0.y*V0.y, V0.z*V0.z, V0.w*V0.w);
                float4 q1 = make_float4(V1.x*V1.x, V1.y*V1.y, V1.z*V1.z, V1.w*V1.w);
                float4 q2 = make_float4(V2.x*V2.x, V2.y*V2.y, V2.z*V2.z, V2.w*V2.w);
                float4 q3 = make_float4(V3.x*V3.x, V3.y*V3.y, V3.z*V3.z, V3.w*V3.w);
                sRV2[0] = f4fma(Ra, q0, sRV2[0]);
                sRV2[1] = f4fma(Ra, q1, sRV2[1]);
                sRV2[2] = f4fma(Ra, q2, sRV2[2]);
                sRV2[3] = f4fma(Ra, q3, sRV2[3]);
                w0 = nw0; w1 = nw1; w2 = nw2; w3 = nw3;
            }
        }

        // combine the 4 mchunks within each wave (lane bits 4,5)
        {
            float* f1 = reinterpret_cast<float*>(sRV);
            float* f2 = reinterpret_cast<float*>(sRV2);
            #pragma unroll
            for (int k = 0; k < 16; ++k) { f1[k] += __shfl_xor(f1[k], 16); f2[k] += __shfl_xor(f2[k], 16); }
            sum_R += __shfl_xor(sum_R, 16);
            #pragma unroll
            for (int k = 0; k < 16; ++k) { f1[k] += __shfl_xor(f1[k], 32); f2[k] += __shfl_xor(f2[k], 32); }
            sum_R += __shfl_xor(sum_R, 32);
        }
        __syncthreads();                    // all psvL reads done before red overwrite
        if ((tid & 48) == 0) {
            float4* dst = &red4[((tid >> 6) * 16 + c_l) * 9];
            dst[0] = make_float4(sum_R, 0.f, 0.f, 0.f);
            dst[1] = sRV[0];  dst[2] = sRV[1];  dst[3] = sRV[2];  dst[4] = sRV[3];
            dst[5] = sRV2[0]; dst[6] = sRV2[1]; dst[7] = sRV2[2]; dst[8] = sRV2[3];
        }
        __syncthreads();

        // -------- epilogue: thread = (h, cc) --------
        {
            const int h  = tid & 15;
            const int cc = tid >> 4;
            float sR = 0.f, sV = 0.f, sV2 = 0.f;
            #pragma unroll
            for (int j = 0; j < 4; ++j) {
                int off = (j * 16 + cc) * 36;
                sR  += uni[off];
                sV  += uni[off + 4 + h];
                sV2 += uni[off + 20 + h];
            }
            float inv = 1.0f / sR;
            float mu  = sV * inv;
            float sig = fmaxf(fmaf(-mu, mu, sV2 * inv), 1e-30f);
            float l2s = lg2(sqrtf(sig) + EPSF);          // log2(sigma+eps)
            float lsum = red16(l2s) * LN2;               // sum_h ln(sigma)
            int   cgi  = chalf * 16 + cc;
            float cost = sR * fmaf(16.0f, beta_v[cgi], lsum);
            float z    = lamv * (beta_a[cgi] - cost);
            float av   = rcpf(1.0f + ex2(-z * LOG2E));
            if (it < 2) {
                muL[cc][h] = mu;
                KL[cc][h]  = (-0.5f * LOG2E) / sig;
                CL[cc][h]  = -(l2s + L2SQ2PI);
                if (h == 0) aL[cc] = av;
            } else {
                int nn   = cgi * NXY + xy;
                int base = (b * CWW + nn) * HH + h;
                mu_out[base] = mu;
                if (h == 0) a_out[b * CWW + nn] = av;
            }
        }
        if (it == 2) return;
        __syncthreads();                    // muL/KL/CL/aL visible; red reads done

        // ========================= pv =========================
        float4 M[4], Kk[4], Cc[4];
        #pragma unroll
        for (int p = 0; p < 4; ++p) {
            M[p]  = make_float4(muL[c_l][4*p+0], muL[c_l][4*p+1], muL[c_l][4*p+2], muL[c_l][4*p+3]);
            Kk[p] = make_float4(KL[c_l][4*p+0],  KL[c_l][4*p+1],  KL[c_l][4*p+2],  KL[c_l][4*p+3]);
            Cc[p] = make_float4(CL[c_l][4*p+0],  CL[c_l][4*p+1],  CL[c_l][4*p+2],  CL[c_l][4*p+3]);
        }
        const float ap = aL[c_l];
        float* rowsIt = rowsG + it * (NB * BKK) + b * BKK;

        {
            const float4* wp = WtB + m0 * 128;
            float4 w0 = wp[0], w1 = wp[32], w2 = wp[64], w3 = wp[96];
            #pragma unroll 1
            for (int i = 0; i < 18; ++i) {
                const int m = m0 + i;
                wp += 128;                               // i=17 -> slack row 288
                float4 nw0 = wp[0], nw1 = wp[32], nw2 = wp[64], nw3 = wp[96];
                float4 P0 = poseS4[m * 4 + 0];
                float4 P1 = poseS4[m * 4 + 1];
                float4 P2 = poseS4[m * 4 + 2];
                float4 P3 = poseS4[m * 4 + 3];
                float4 V0 = f4fma(w0.w, P3, f4fma(w0.z, P2, f4fma(w0.y, P1, f4mul(w0.x, P0))));
                float4 V1 = f4fma(w1.w, P3, f4fma(w1.z, P2, f4fma(w1.y, P1, f4mul(w1.x, P0))));
                float4 V2 = f4fma(w2.w, P3, f4fma(w2.z, P2, f4fma(w2.y, P1, f4mul(w2.x, P0))));
                float4 V3 = f4fma(w3.w, P3, f4fma(w3.z, P2, f4fma(w3.y, P1, f4mul(w3.x, P0))));

                float psv = 0.0f;
                {
                    float4 t, g;
                    t = make_float4(V0.x-M[0].x, V0.y-M[0].y, V0.z-M[0].z, V0.w-M[0].w);
                    g = make_float4(fmaf(t.x*t.x, Kk[0].x, Cc[0].x), fmaf(t.y*t.y, Kk[0].y, Cc[0].y),
                                    fmaf(t.z*t.z, Kk[0].z, Cc[0].z), fmaf(t.w*t.w, Kk[0].w, Cc[0].w));
                    psv += ex2(g.x) + ex2(g.y) + ex2(g.z) + ex2(g.w);
                    t = make_float4(V1.x-M[1].x, V1.y-M[1].y, V1.z-M[1].z, V1.w-M[1].w);
                    g = make_float4(fmaf(t.x*t.x, Kk[1].x, Cc[1].x), fmaf(t.y*t.y, Kk[1].y, Cc[1].y),
                                    fmaf(t.z*t.z, Kk[1].z, Cc[1].z), fmaf(t.w*t.w, Kk[1].w, Cc[1].w));
                    psv += ex2(g.x) + ex2(g.y) + ex2(g.z) + ex2(g.w);
                    t = make_float4(V2.x-M[2].x, V2.y-M[2].y, V2.z-M[2].z, V2.w-M[2].w);
                    g = make_float4(fmaf(t.x*t.x, Kk[2].x, Cc[2].x), fmaf(t.y*t.y, Kk[2].y, Cc[2].y),
                                    fmaf(t.z*t.z, Kk[2].z, Cc[2].z), fmaf(t.w*t.w, Kk[2].w, Cc[2].w));
                    psv += ex2(g.x) + ex2(g.y) + ex2(g.z) + ex2(g.w);
                    t = make_float4(V3.x-M[3].x, V3.y-M[3].y, V3.z-M[3].z, V3.w-M[3].w);
                    g = make_float4(fmaf(t.x*t.x, Kk[3].x, Cc[3].x), fmaf(t.y*t.y, Kk[3].y, Cc[3].y),
                                    fmaf(t.z*t.z, Kk[3].z, Cc[3].z), fmaf(t.w*t.w, Kk[3].w, Cc[3].w));
                    psv += ex2(g.x) + ex2(g.y) + ex2(g.z) + ex2(g.w);
                }
                uni[m * 17 + c_l] = psv;        // psvL, bank-conflict-padded

                float rv = ap * psv;
                rv += __shfl_xor(rv, 1);
                rv += __shfl_xor(rv, 2);
                rv += __shfl_xor(rv, 4);
                rv += __shfl_xor(rv, 8);
                if (c_l == 0)
                    __hip_atomic_fetch_add(&rowsIt[m], rv,
                                           __ATOMIC_RELAXED, __HIP_MEMORY_SCOPE_AGENT);
                w0 = nw0; w1 = nw1; w2 = nw2; w3 = nw3;
            }
        }

        b_barrier(bcnt, bgen);
        asm volatile("" ::: "memory");

        // -------- AE update from completed row sums (coherent atomic loads) ----
        for (int m = tid; m < BKK; m += 256) {
            float s = __hip_atomic_load(&rowsIt[m], __ATOMIC_RELAXED, __HIP_MEMORY_SCOPE_AGENT);
            float invr = 1.0f / (s + EPSF);
            float am = amL[m];
            AE[m] = make_float2(am * invr, EPSF * am);
        }
        __syncthreads();
    }
}

extern "C" void kernel_launch(void* const* d_in, const int* in_sizes, int n_in,
                              void* d_out, int out_size, void* d_ws, size_t ws_size,
                              hipStream_t stream) {
    const float* poses  = (const float*)d_in[0];
    const float* act    = (const float*)d_in[1];
    const float* W      = (const float*)d_in[2];
    const float* beta_v = (const float*)d_in[3];
    const float* beta_a = (const float*)d_in[4];
    const float* lam    = (const float*)d_in[5];
    float* out = (float*)d_out;
    float* ws  = (float*)d_ws;

    const int SZ = NB * CWW * HH;            // 147456
    float* Wt    = ws;                       // (288+1)*128 float4 = 147968 floats (slack row)
    float* rowsG = Wt + 289 * 512;           // 2*8*288 = 4608 floats
    unsigned* bar = (unsigned*)(rowsG + 2 * NB * BKK);  // 8*32 uints

    wt_kernel<<<dim3(144), dim3(256), 0, stream>>>(
        (const float4*)W, (float4*)Wt, rowsG, bar);

    const float4* Wt4 = (const float4*)Wt;
    fused_em<<<dim3(NBLK), dim3(256), 0, stream>>>(
        poses, act, Wt4, beta_v, beta_a, lam,
        rowsG, bar, out, out + SZ);
}